// Round 5
// baseline (149.257 us; speedup 1.0000x reference)
//
#include <hip/hip_runtime.h>
#include <hip/hip_bf16.h>
#include <math.h>

#define NN 4096
#define DD 128

typedef __attribute__((ext_vector_type(8))) short bf16x8;
typedef __attribute__((ext_vector_type(4))) float f32x4;

// ws layout (doubles): accumulator slots ws[k*8], k=0..15 (64B apart);
// ws[128]=bqc1, ws[129]=bqc2, ws[130]=fdc.

// ---- convert F (f32 [d][i]) -> bf16 transposed [i][d] (for log_kernel) ----
__global__ __launch_bounds__(256)
void convert_t_kernel(const float* __restrict__ FP, const float* __restrict__ FM,
                      __hip_bfloat16* __restrict__ FPt, __hip_bfloat16* __restrict__ FMt)
{
    const float* src = blockIdx.y ? FM : FP;
    __hip_bfloat16* dst = blockIdx.y ? FMt : FPt;
    const int t  = threadIdx.x;
    const int il = t & 127;
    const int dh = t >> 7;
    const int i  = blockIdx.x * 128 + il;
    #pragma unroll
    for (int it = 0; it < 8; ++it) {
        const int d0 = dh * 64 + it * 8;
        union { __hip_bfloat162 h[4]; bf16x8 v; } p;
        #pragma unroll
        for (int j = 0; j < 4; ++j) {
            const float a = src[(long)(d0 + 2*j)     * NN + i];
            const float b = src[(long)(d0 + 2*j + 1) * NN + i];
            p.h[j] = __float22bfloat162_rn(make_float2(a, b));
        }
        *(bf16x8*)&dst[(long)i * DD + d0] = p.v;
    }
}

// ---- convert F (f32 [d][i]) -> bf16 SAME layout [d][i] (for dot_kernel B) --
__global__ __launch_bounds__(256)
void convert_d_kernel(const float* __restrict__ FP, const float* __restrict__ FM,
                      __hip_bfloat16* __restrict__ FPd, __hip_bfloat16* __restrict__ FMd)
{
    const int total = DD * NN / 4;
    for (int idx = blockIdx.x * blockDim.x + threadIdx.x; idx < 2 * total;
         idx += gridDim.x * blockDim.x) {
        const bool second = idx >= total;
        const float4 v = ((const float4*)(second ? FM : FP))[second ? idx - total : idx];
        union { __hip_bfloat162 h[2]; uint2 u; } p;
        p.h[0] = __float22bfloat162_rn(make_float2(v.x, v.y));
        p.h[1] = __float22bfloat162_rn(make_float2(v.z, v.w));
        ((uint2*)(second ? FMd : FPd))[second ? idx - total : idx] = p.u;
    }
}

// ---- log term: sum log(1 + 0.5*C + eps), C = Fa_t^T-style Gram, NO S. ------
// Symmetry: z=1,2 compute only tj>=ti tiles (x2 off-diag, per-element on diag).
// 2080 blocks: [0,1024) -> z0 full grid; then 528+528 triangular.
__global__ __launch_bounds__(256, 3)
void log_kernel(const __hip_bfloat16* __restrict__ FPt_,
                const __hip_bfloat16* __restrict__ FMt_, double* __restrict__ accum)
{
    const int bid = blockIdx.x;
    int z, ti, tj;
    if (bid < 1024) { z = 0; ti = bid >> 5; tj = bid & 31; }
    else {
        int q = bid - 1024;
        z = 1 + (q >= 528);
        int u = (q >= 528) ? q - 528 : q;
        ti = 0;
        while (u >= 32 - ti) { u -= 32 - ti; ++ti; }
        tj = ti + u;
    }
    const short* Fa = (const short*)((z == 2) ? FMt_ : FPt_);
    const short* Fb = (const short*)((z == 0) ? FMt_ : (z == 1) ? FPt_ : FMt_);
    const float onep = 1.0f + ((z == 0) ? 0.0f : 1e-8f);

    const int t = threadIdx.x;
    const int lane = t & 63, wid = t >> 6;
    const int wr = wid >> 1, wc = wid & 1;
    const int l15 = lane & 15, l4 = lane >> 4;
    const int i0 = ti * 128 + wr * 64;
    const int j0 = tj * 128 + wc * 64;

    // wave-level weighting
    const bool diagTile = (z > 0) && (ti == tj);
    const bool skip     = diagTile && (wr > wc);
    const bool perElem  = diagTile && (wr == wc);
    const bool dbl      = (z > 0) && ((ti < tj) || (diagTile && wr < wc));

    const short* pa = Fa + (long)(i0 + l15) * DD + l4 * 8;
    const short* pb = Fb + (long)(j0 + l15) * DD + l4 * 8;

    float lsum = 0.f;
    if (!skip) {
        bf16x8 Aa[4], Ab[4], Ba[4], Bb[4];
        #pragma unroll
        for (int m = 0; m < 4; ++m) {
            Aa[m] = *(const bf16x8*)(pa + m * (16 * DD));
            Ab[m] = *(const bf16x8*)(pb + m * (16 * DD));
        }
        f32x4 acc[4][4] = {};
        #pragma unroll
        for (int kb = 0; kb < 4; ++kb) {
            if (kb == 0 || kb == 2) {           // prefetch kb+1 into B buffers
                if (kb < 3) {
                    #pragma unroll
                    for (int m = 0; m < 4; ++m) {
                        Ba[m] = *(const bf16x8*)(pa + m * (16 * DD) + (kb + 1) * 32);
                        Bb[m] = *(const bf16x8*)(pb + m * (16 * DD) + (kb + 1) * 32);
                    }
                }
                #pragma unroll
                for (int m = 0; m < 4; ++m)
                    #pragma unroll
                    for (int n = 0; n < 4; ++n)
                        acc[m][n] = __builtin_amdgcn_mfma_f32_16x16x32_bf16(Aa[m], Ab[n], acc[m][n], 0, 0, 0);
            } else {                            // prefetch kb+1 into A buffers
                if (kb < 3) {
                    #pragma unroll
                    for (int m = 0; m < 4; ++m) {
                        Aa[m] = *(const bf16x8*)(pa + m * (16 * DD) + (kb + 1) * 32);
                        Ab[m] = *(const bf16x8*)(pb + m * (16 * DD) + (kb + 1) * 32);
                    }
                }
                #pragma unroll
                for (int m = 0; m < 4; ++m)
                    #pragma unroll
                    for (int n = 0; n < 4; ++n)
                        acc[m][n] = __builtin_amdgcn_mfma_f32_16x16x32_bf16(Ba[m], Bb[n], acc[m][n], 0, 0, 0);
            }
        }
        #pragma unroll
        for (int m = 0; m < 4; ++m)
            #pragma unroll
            for (int n = 0; n < 4; ++n)
                #pragma unroll
                for (int r = 0; r < 4; ++r) {
                    const float term = __logf(fmaf(0.5f, acc[m][n][r], onep));
                    if (perElem) {
                        const int il = m * 16 + l4 * 4 + r;
                        const int jl = n * 16 + l15;
                        const float w = (jl > il) ? 2.f : ((jl == il) ? 1.f : 0.f);
                        lsum = fmaf(w, term, lsum);
                    } else {
                        lsum += term;
                    }
                }
        if (dbl) lsum *= 2.f;
    }

    float v = lsum;
    #pragma unroll
    for (int off = 32; off; off >>= 1) v += __shfl_down(v, off);
    if (lane == 0 && !skip)
        atomicAdd(accum + ((bid & 15) << 3), (double)v);
}

// ---- dot term: -0.5 * sum_{i,j} S[i,j]*C[i,j] via V = S*Fb^T then <V,Fa^T>.
// S is the MFMA A-operand: lane reads 8 consecutive j (2x dwordx4) -> cvt bf16.
// 768 blocks x 4 waves = 3072 waves: wave = z(3) x ksplit(8) x istrip(128).
__global__ __launch_bounds__(256, 3)
void dot_kernel(const float* __restrict__ SU, const float* __restrict__ SP,
                const float* __restrict__ SM,
                const __hip_bfloat16* __restrict__ FPd_,
                const __hip_bfloat16* __restrict__ FMd_,
                const float* __restrict__ FPf, const float* __restrict__ FMf,
                double* __restrict__ accum)
{
    const int t = threadIdx.x;
    const int lane = t & 63, wid = t >> 6;
    const int l15 = lane & 15, l4 = lane >> 4;
    const int w = blockIdx.x * 4 + wid;        // 0..3071
    const int z = w >> 10;
    const int rem = w & 1023;
    const int ks = rem & 7;                    // K split 0..7 (j range of 512)
    const int is = rem >> 3;                   // i strip 0..127 (32 rows)

    const float* S  = (z == 0) ? SU : (z == 1) ? SP : SM;
    const short* Fb = (const short*)((z == 1) ? FPd_ : FMd_);
    const float* Fa = (z == 2) ? FMf : FPf;

    const int i0 = is * 32;
    const int jb = ks * 512;

    f32x4 acc[2][8] = {};
    const float* srow0 = S + (long)(i0 + l15) * NN + l4 * 8;       // m=0 row
    const float* srow1 = srow0 + 16 * NN;                          // m=1 row
    const short* fbp   = Fb + (long)l15 * NN + l4 * 8;

    #pragma unroll 2
    for (int c = 0; c < 16; ++c) {
        const int jc = jb + c * 32;
        // A fragments: S rows, 8 consecutive f32 -> bf16x8
        bf16x8 aS[2];
        {
            const float4 lo0 = *(const float4*)(srow0 + jc);
            const float4 hi0 = *(const float4*)(srow0 + jc + 4);
            const float4 lo1 = *(const float4*)(srow1 + jc);
            const float4 hi1 = *(const float4*)(srow1 + jc + 4);
            union { __hip_bfloat162 h[4]; bf16x8 v; } p0, p1;
            p0.h[0] = __float22bfloat162_rn(make_float2(lo0.x, lo0.y));
            p0.h[1] = __float22bfloat162_rn(make_float2(lo0.z, lo0.w));
            p0.h[2] = __float22bfloat162_rn(make_float2(hi0.x, hi0.y));
            p0.h[3] = __float22bfloat162_rn(make_float2(hi0.z, hi0.w));
            p1.h[0] = __float22bfloat162_rn(make_float2(lo1.x, lo1.y));
            p1.h[1] = __float22bfloat162_rn(make_float2(lo1.z, lo1.w));
            p1.h[2] = __float22bfloat162_rn(make_float2(hi1.x, hi1.y));
            p1.h[3] = __float22bfloat162_rn(make_float2(hi1.z, hi1.w));
            aS[0] = p0.v; aS[1] = p1.v;
        }
        // B fragments: Fb [d][j] bf16, 8 consecutive j per lane
        bf16x8 bF[8];
        #pragma unroll
        for (int n = 0; n < 8; ++n)
            bF[n] = *(const bf16x8*)(fbp + (long)n * 16 * NN + jc);
        #pragma unroll
        for (int m = 0; m < 2; ++m)
            #pragma unroll
            for (int n = 0; n < 8; ++n)
                acc[m][n] = __builtin_amdgcn_mfma_f32_16x16x32_bf16(aS[m], bF[n], acc[m][n], 0, 0, 0);
    }

    // contract partial V[i,d] with Fa[d,i] (f32 original layout)
    float lsum = 0.f;
    #pragma unroll
    for (int m = 0; m < 2; ++m)
        #pragma unroll
        for (int n = 0; n < 8; ++n) {
            const long drow = (long)(n * 16 + l15) * NN + i0 + m * 16 + l4 * 4;
            #pragma unroll
            for (int r = 0; r < 4; ++r)
                lsum = fmaf(acc[m][n][r], Fa[drow + r], lsum);
        }

    float v = lsum;
    #pragma unroll
    for (int off = 32; off; off >>= 1) v += __shfl_down(v, off);
    if (lane == 0)
        atomicAdd(accum + ((blockIdx.x & 15) << 3), (double)(-0.5 * v));
}

// ---------------- fallback path (round-2 kernel, used if ws too small) ------
__global__ __launch_bounds__(256, 2)
void gemm_loss_mfma(const float* __restrict__ S, const float* __restrict__ F1,
                    const float* __restrict__ F2, float eps, double* __restrict__ accum)
{
    __shared__ char lds[2][128 * 256];
    __shared__ float red[4];
    const int t  = threadIdx.x;
    const int i0 = blockIdx.y * 128;
    const int j0 = blockIdx.x * 128;
    {
        const int il   = t & 127;
        const int half = t >> 7;
        const float* c1 = F1 + i0 + il;
        const float* c2 = F2 + j0 + il;
        char* r1 = lds[0] + il * 256;
        char* r2 = lds[1] + il * 256;
        #pragma unroll
        for (int it = 0; it < 8; ++it) {
            const int q  = half * 8 + it;
            const int d0 = q * 8;
            float a[8], b[8];
            #pragma unroll
            for (int j = 0; j < 8; ++j) {
                a[j] = c1[(long)(d0 + j) * NN];
                b[j] = c2[(long)(d0 + j) * NN];
            }
            union { __hip_bfloat162 h[4]; bf16x8 v; } pa, pb;
            #pragma unroll
            for (int j = 0; j < 4; ++j) {
                pa.h[j] = __float22bfloat162_rn(make_float2(a[2*j], a[2*j+1]));
                pb.h[j] = __float22bfloat162_rn(make_float2(b[2*j], b[2*j+1]));
            }
            const int off = (q ^ (il & 15)) << 4;
            *(bf16x8*)(r1 + off) = pa.v;
            *(bf16x8*)(r2 + off) = pb.v;
        }
    }
    __syncthreads();
    const int lane = t & 63;
    const int wid  = t >> 6;
    const int wr   = wid >> 1, wc = wid & 1;
    const int l15  = lane & 15, l4 = lane >> 4;
    float sreg[4][4][4];
    #pragma unroll
    for (int am = 0; am < 4; ++am)
        #pragma unroll
        for (int r = 0; r < 4; ++r) {
            const long gi    = (long)(i0 + wr * 64 + am * 16 + l4 * 4 + r);
            const long basep = gi * NN + j0 + wc * 64 + l15;
            #pragma unroll
            for (int bn = 0; bn < 4; ++bn)
                sreg[am][bn][r] = S[basep + bn * 16];
        }
    f32x4 acc[4][4] = {};
    #pragma unroll
    for (int kb = 0; kb < 4; ++kb) {
        bf16x8 af[4], bgr[4];
        #pragma unroll
        for (int m = 0; m < 4; ++m) {
            const int ia = wr * 64 + m * 16 + l15;
            af[m] = *(const bf16x8*)(lds[0] + ia * 256 + (((kb * 4 + l4) ^ l15) << 4));
            const int jbq = wc * 64 + m * 16 + l15;
            bgr[m] = *(const bf16x8*)(lds[1] + jbq * 256 + (((kb * 4 + l4) ^ l15) << 4));
        }
        #pragma unroll
        for (int m = 0; m < 4; ++m)
            #pragma unroll
            for (int n = 0; n < 4; ++n)
                acc[m][n] = __builtin_amdgcn_mfma_f32_16x16x32_bf16(af[m], bgr[n], acc[m][n], 0, 0, 0);
    }
    float lsum = 0.f;
    #pragma unroll
    for (int m = 0; m < 4; ++m)
        #pragma unroll
        for (int n = 0; n < 4; ++n)
            #pragma unroll
            for (int r = 0; r < 4; ++r) {
                const float o = 0.5f * acc[m][n][r];
                lsum += fmaf(-sreg[m][n][r], o, __logf(1.0f + o + eps));
            }
    float v = lsum;
    #pragma unroll
    for (int off = 32; off; off >>= 1) v += __shfl_down(v, off);
    if ((t & 63) == 0) red[t >> 6] = v;
    __syncthreads();
    if (t == 0) {
        const float tot = red[0] + red[1] + red[2] + red[3];
        atomicAdd(accum, (double)tot);   // slot 0
    }
}

// ---------------- small kernels ----------------
__global__ __launch_bounds__(256)
void bqc_kernel(const float* __restrict__ FP, const float* __restrict__ FM,
                const float* __restrict__ B, double* __restrict__ ws)
{
    __shared__ float red1[4], red2[4];
    const int n4 = DD * NN / 4;
    float s1 = 0.f, s2 = 0.f;
    for (int i = blockIdx.x * blockDim.x + threadIdx.x; i < n4;
         i += gridDim.x * blockDim.x) {
        const float4 p = ((const float4*)FP)[i];
        const float4 m = ((const float4*)FM)[i];
        const float4 b = ((const float4*)B)[i];
        float d;
        d = p.x - b.x; s1 += d * d;  d = p.y - b.y; s1 += d * d;
        d = p.z - b.z; s1 += d * d;  d = p.w - b.w; s1 += d * d;
        d = m.x - b.x; s2 += d * d;  d = m.y - b.y; s2 += d * d;
        d = m.z - b.z; s2 += d * d;  d = m.w - b.w; s2 += d * d;
    }
    const int t = threadIdx.x;
    #pragma unroll
    for (int off = 32; off; off >>= 1) {
        s1 += __shfl_down(s1, off);
        s2 += __shfl_down(s2, off);
    }
    if ((t & 63) == 0) { red1[t >> 6] = s1; red2[t >> 6] = s2; }
    __syncthreads();
    if (t == 0) {
        atomicAdd(&ws[128], (double)(red1[0] + red1[1] + red1[2] + red1[3]));
        atomicAdd(&ws[129], (double)(red2[0] + red2[1] + red2[2] + red2[3]));
    }
}

__global__ __launch_bounds__(256)
void fdc_kernel(const float* __restrict__ FP, const float* __restrict__ FM,
                double* __restrict__ ws)
{
    __shared__ float red[4];
    const float* F = (blockIdx.x >= DD) ? FM : FP;
    const int row = blockIdx.x & (DD - 1);
    float s = 0.f;
    const float4* rowp = (const float4*)&F[(long)row * NN];
    for (int i = threadIdx.x; i < NN / 4; i += blockDim.x) {
        const float4 v = rowp[i];
        s += v.x + v.y + v.z + v.w;
    }
    const int t = threadIdx.x;
    #pragma unroll
    for (int off = 32; off; off >>= 1) s += __shfl_down(s, off);
    if ((t & 63) == 0) red[t >> 6] = s;
    __syncthreads();
    if (t == 0) {
        const double rs = (double)(red[0] + red[1] + red[2] + red[3]);
        atomicAdd(&ws[130], rs * rs);
    }
}

__global__ void finalize_kernel(const double* __restrict__ ws, float* __restrict__ out)
{
    if (threadIdx.x == 0 && blockIdx.x == 0) {
        double s = 0.0;
        #pragma unroll
        for (int k = 0; k < 16; ++k) s += ws[k * 8];
        out[0] = (float)(s + ws[130] + sqrt(ws[128]) + sqrt(ws[129]));
    }
}

extern "C" void kernel_launch(void* const* d_in, const int* in_sizes, int n_in,
                              void* d_out, int out_size, void* d_ws, size_t ws_size,
                              hipStream_t stream)
{
    const float* SU = (const float*)d_in[0];
    const float* SP = (const float*)d_in[1];
    const float* SM = (const float*)d_in[2];
    const float* FP = (const float*)d_in[3];
    const float* FM = (const float*)d_in[4];
    const float* B  = (const float*)d_in[5];
    float*  out = (float*)d_out;
    double* ws  = (double*)d_ws;

    hipMemsetAsync(d_ws, 0, 4096, stream);

    const size_t fb = (size_t)NN * DD * sizeof(__hip_bfloat16);   // 1 MB
    const size_t need = 4096 + 4 * fb;

    if (ws_size >= need) {
        char* base = (char*)d_ws + 4096;
        __hip_bfloat16* FPt = (__hip_bfloat16*)(base);
        __hip_bfloat16* FMt = (__hip_bfloat16*)(base + fb);
        __hip_bfloat16* FPd = (__hip_bfloat16*)(base + 2 * fb);
        __hip_bfloat16* FMd = (__hip_bfloat16*)(base + 3 * fb);
        convert_t_kernel<<<dim3(NN / 128, 2), 256, 0, stream>>>(FP, FM, FPt, FMt);
        convert_d_kernel<<<512, 256, 0, stream>>>(FP, FM, FPd, FMd);
        log_kernel<<<2080, 256, 0, stream>>>(FPt, FMt, ws);
        dot_kernel<<<768, 256, 0, stream>>>(SU, SP, SM, FPd, FMd, FP, FM, ws);
    } else {
        dim3 grid(NN / 128, NN / 128);
        gemm_loss_mfma<<<grid, 256, 0, stream>>>(SU, FP, FM, 0.0f, ws);
        gemm_loss_mfma<<<grid, 256, 0, stream>>>(SP, FP, FP, 1e-8f, ws);
        gemm_loss_mfma<<<grid, 256, 0, stream>>>(SM, FM, FM, 1e-8f, ws);
    }
    bqc_kernel<<<512, 256, 0, stream>>>(FP, FM, B, ws);
    fdc_kernel<<<256, 256, 0, stream>>>(FP, FM, ws);
    finalize_kernel<<<1, 64, 0, stream>>>(ws, out);
}

// Round 6
// 123.509 us; speedup vs baseline: 1.2085x; 1.2085x over previous
//
#include <hip/hip_runtime.h>
#include <hip/hip_bf16.h>
#include <math.h>

#define NN 4096
#define DD 128

typedef __attribute__((ext_vector_type(8))) short bf16x8;
typedef __attribute__((ext_vector_type(4))) float f32x4;

// ws layout (doubles): gemm-loss slots ws[k*8], k=0..15; ws[128]=bqc1,
// ws[129]=bqc2, ws[130]=fdc.

__device__ __forceinline__ void gload_lds16(const float* g, float* l) {
    __builtin_amdgcn_global_load_lds((const __attribute__((address_space(1))) char*)g,
                                     (__attribute__((address_space(3))) char*)l, 16, 0, 0);
}

// ---- convert F (f32 [d][i], column-reads coalesced) -> bf16 [i][d] ----
__global__ __launch_bounds__(256)
void convert_t_kernel(const float* __restrict__ FP, const float* __restrict__ FM,
                      __hip_bfloat16* __restrict__ FPt, __hip_bfloat16* __restrict__ FMt)
{
    const float* src = blockIdx.y ? FM : FP;
    __hip_bfloat16* dst = blockIdx.y ? FMt : FPt;
    const int t  = threadIdx.x;
    const int il = t & 127;
    const int dh = t >> 7;
    const int i  = blockIdx.x * 128 + il;
    #pragma unroll
    for (int it = 0; it < 8; ++it) {
        const int d0 = dh * 64 + it * 8;
        union { __hip_bfloat162 h[4]; bf16x8 v; } p;
        #pragma unroll
        for (int j = 0; j < 4; ++j) {
            const float a = src[(long)(d0 + 2*j)     * NN + i];
            const float b = src[(long)(d0 + 2*j + 1) * NN + i];
            p.h[j] = __float22bfloat162_rn(make_float2(a, b));
        }
        *(bf16x8*)&dst[(long)i * DD + d0] = p.v;
    }
}

// ---- fused gemm-loss: sum over all (i,j,z) of -S*omega + log(1+omega+eps) --
// 512 blocks x 4 waves = 2048 waves; wave-tile = 64 i x 32 j; 12 tiles/wave,
// G = w + t*2048 over (z, it, jt). jt is constant per wave.
// Per tile: [24 frag loads (L2 bf16 F)] [8 global_load_lds S(t+1)]
// [s_waitcnt vmcnt(8): frags+S(t) done, S(t+1) stays in flight] [32 MFMA]
// [epilogue from LDS]. No __syncthreads anywhere -> the S stream never drains.
__global__ __launch_bounds__(256, 2)
void gemm_loss_fused(const float* __restrict__ SU, const float* __restrict__ SP,
                     const float* __restrict__ SM,
                     const __hip_bfloat16* __restrict__ FPt_,
                     const __hip_bfloat16* __restrict__ FMt_,
                     double* __restrict__ accum)
{
    __shared__ float sS[4][2][64 * 32];    // per-wave double-buffered S tile
    const int t0   = threadIdx.x;
    const int lane = t0 & 63, wid = t0 >> 6;
    const int l15  = lane & 15, l4 = lane >> 4;
    const int w    = blockIdx.x * 4 + wid;              // 0..2047
    const short* FPt = (const short*)FPt_;
    const short* FMt = (const short*)FMt_;

#define STAGE(G_, buf_)                                                        \
    {                                                                          \
        const int z_  = (G_) >> 13;                                            \
        const float* S_ = (z_ == 0) ? SU : (z_ == 1) ? SP : SM;                \
        const int i0_ = (((G_) >> 7) & 63) << 6;                               \
        const int j0_ = ((G_) & 127) << 5;                                     \
        const float* src_ = S_ + (long)(i0_ + (lane >> 3)) * NN + j0_ + (lane & 7) * 4; \
        _Pragma("unroll")                                                      \
        for (int q_ = 0; q_ < 8; ++q_)                                         \
            gload_lds16(src_ + (long)q_ * 8 * NN, &sS[wid][buf_][q_ * 256]);   \
    }

    float lsum = 0.f;
    STAGE(w, 0);                                        // prologue: S(0)

    #pragma unroll 1
    for (int t = 0; t < 12; ++t) {
        const int G  = w + t * 2048;
        const int z  = G >> 13;
        const int i0 = ((G >> 7) & 63) << 6;
        const int j0 = (G & 127) << 5;
        const short* Fa = (z == 2) ? FMt : FPt;
        const short* Fb = (z == 1) ? FPt : FMt;
        const float onep = (z == 0) ? 1.0f : 1.0f + 1e-8f;

        // 1) fragment loads FIRST (vmcnt is FIFO)
        bf16x8 af[4][4], bg[4][2];
        #pragma unroll
        for (int kb = 0; kb < 4; ++kb) {
            #pragma unroll
            for (int m = 0; m < 4; ++m)
                af[kb][m] = *(const bf16x8*)&Fa[(long)(i0 + m * 16 + l15) * DD + kb * 32 + l4 * 8];
            #pragma unroll
            for (int n = 0; n < 2; ++n)
                bg[kb][n] = *(const bf16x8*)&Fb[(long)(j0 + n * 16 + l15) * DD + kb * 32 + l4 * 8];
        }

        // 2) stage next S tile into the other buffer
        if (t < 11) STAGE(G + 2048, (t + 1) & 1);

        // 3) counted wait: frags + S(t) complete, S(t+1) (8 newest) in flight
        __builtin_amdgcn_sched_barrier(0);
        if (t < 11) asm volatile("s_waitcnt vmcnt(8)");
        else        asm volatile("s_waitcnt vmcnt(0)");
        __builtin_amdgcn_sched_barrier(0);

        // 4) MFMAs
        f32x4 acc[4][2] = {};
        #pragma unroll
        for (int kb = 0; kb < 4; ++kb)
            #pragma unroll
            for (int m = 0; m < 4; ++m)
                #pragma unroll
                for (int n = 0; n < 2; ++n)
                    acc[m][n] = __builtin_amdgcn_mfma_f32_16x16x32_bf16(af[kb][m], bg[kb][n], acc[m][n], 0, 0, 0);

        // 5) epilogue: S from own LDS buffer (C/D layout: col=l15, row=l4*4+r)
        const float* curS = &sS[wid][t & 1][0];
        #pragma unroll
        for (int m = 0; m < 4; ++m)
            #pragma unroll
            for (int n = 0; n < 2; ++n)
                #pragma unroll
                for (int r = 0; r < 4; ++r) {
                    const float s = curS[(m * 16 + l4 * 4 + r) * 32 + n * 16 + l15];
                    const float o = 0.5f * acc[m][n][r];
                    lsum += fmaf(-s, o, __logf(o + onep));
                }
    }
#undef STAGE

    float v = lsum;
    #pragma unroll
    for (int off = 32; off; off >>= 1) v += __shfl_down(v, off);
    if (lane == 0)
        atomicAdd(accum + ((w & 15) << 3), (double)v);
}

// ---------------- fallback path (round-2 kernel, used if ws too small) ------
__global__ __launch_bounds__(256, 2)
void gemm_loss_mfma(const float* __restrict__ S, const float* __restrict__ F1,
                    const float* __restrict__ F2, float eps, double* __restrict__ accum)
{
    __shared__ char lds[2][128 * 256];
    __shared__ float red[4];
    const int t  = threadIdx.x;
    const int i0 = blockIdx.y * 128;
    const int j0 = blockIdx.x * 128;
    {
        const int il   = t & 127;
        const int half = t >> 7;
        const float* c1 = F1 + i0 + il;
        const float* c2 = F2 + j0 + il;
        char* r1 = lds[0] + il * 256;
        char* r2 = lds[1] + il * 256;
        #pragma unroll
        for (int it = 0; it < 8; ++it) {
            const int q  = half * 8 + it;
            const int d0 = q * 8;
            float a[8], b[8];
            #pragma unroll
            for (int j = 0; j < 8; ++j) {
                a[j] = c1[(long)(d0 + j) * NN];
                b[j] = c2[(long)(d0 + j) * NN];
            }
            union { __hip_bfloat162 h[4]; bf16x8 v; } pa, pb;
            #pragma unroll
            for (int j = 0; j < 4; ++j) {
                pa.h[j] = __float22bfloat162_rn(make_float2(a[2*j], a[2*j+1]));
                pb.h[j] = __float22bfloat162_rn(make_float2(b[2*j], b[2*j+1]));
            }
            const int off = (q ^ (il & 15)) << 4;
            *(bf16x8*)(r1 + off) = pa.v;
            *(bf16x8*)(r2 + off) = pb.v;
        }
    }
    __syncthreads();
    const int lane = t & 63;
    const int wid  = t >> 6;
    const int wr   = wid >> 1, wc = wid & 1;
    const int l15  = lane & 15, l4 = lane >> 4;
    float sreg[4][4][4];
    #pragma unroll
    for (int am = 0; am < 4; ++am)
        #pragma unroll
        for (int r = 0; r < 4; ++r) {
            const long gi    = (long)(i0 + wr * 64 + am * 16 + l4 * 4 + r);
            const long basep = gi * NN + j0 + wc * 64 + l15;
            #pragma unroll
            for (int bn = 0; bn < 4; ++bn)
                sreg[am][bn][r] = S[basep + bn * 16];
        }
    f32x4 acc[4][4] = {};
    #pragma unroll
    for (int kb = 0; kb < 4; ++kb) {
        bf16x8 af[4], bgr[4];
        #pragma unroll
        for (int m = 0; m < 4; ++m) {
            const int ia = wr * 64 + m * 16 + l15;
            af[m] = *(const bf16x8*)(lds[0] + ia * 256 + (((kb * 4 + l4) ^ l15) << 4));
            const int jbq = wc * 64 + m * 16 + l15;
            bgr[m] = *(const bf16x8*)(lds[1] + jbq * 256 + (((kb * 4 + l4) ^ l15) << 4));
        }
        #pragma unroll
        for (int m = 0; m < 4; ++m)
            #pragma unroll
            for (int n = 0; n < 4; ++n)
                acc[m][n] = __builtin_amdgcn_mfma_f32_16x16x32_bf16(af[m], bgr[n], acc[m][n], 0, 0, 0);
    }
    float lsum = 0.f;
    #pragma unroll
    for (int m = 0; m < 4; ++m)
        #pragma unroll
        for (int n = 0; n < 4; ++n)
            #pragma unroll
            for (int r = 0; r < 4; ++r) {
                const float o = 0.5f * acc[m][n][r];
                lsum += fmaf(-sreg[m][n][r], o, __logf(1.0f + o + eps));
            }
    float v = lsum;
    #pragma unroll
    for (int off = 32; off; off >>= 1) v += __shfl_down(v, off);
    if ((t & 63) == 0) red[t >> 6] = v;
    __syncthreads();
    if (t == 0) {
        const float tot = red[0] + red[1] + red[2] + red[3];
        atomicAdd(accum, (double)tot);   // slot 0
    }
}

// ---------------- small kernels ----------------
__global__ __launch_bounds__(256)
void bqc_kernel(const float* __restrict__ FP, const float* __restrict__ FM,
                const float* __restrict__ B, double* __restrict__ ws)
{
    __shared__ float red1[4], red2[4];
    const int n4 = DD * NN / 4;
    float s1 = 0.f, s2 = 0.f;
    for (int i = blockIdx.x * blockDim.x + threadIdx.x; i < n4;
         i += gridDim.x * blockDim.x) {
        const float4 p = ((const float4*)FP)[i];
        const float4 m = ((const float4*)FM)[i];
        const float4 b = ((const float4*)B)[i];
        float d;
        d = p.x - b.x; s1 += d * d;  d = p.y - b.y; s1 += d * d;
        d = p.z - b.z; s1 += d * d;  d = p.w - b.w; s1 += d * d;
        d = m.x - b.x; s2 += d * d;  d = m.y - b.y; s2 += d * d;
        d = m.z - b.z; s2 += d * d;  d = m.w - b.w; s2 += d * d;
    }
    const int t = threadIdx.x;
    #pragma unroll
    for (int off = 32; off; off >>= 1) {
        s1 += __shfl_down(s1, off);
        s2 += __shfl_down(s2, off);
    }
    if ((t & 63) == 0) { red1[t >> 6] = s1; red2[t >> 6] = s2; }
    __syncthreads();
    if (t == 0) {
        atomicAdd(&ws[128], (double)(red1[0] + red1[1] + red1[2] + red1[3]));
        atomicAdd(&ws[129], (double)(red2[0] + red2[1] + red2[2] + red2[3]));
    }
}

__global__ __launch_bounds__(256)
void fdc_kernel(const float* __restrict__ FP, const float* __restrict__ FM,
                double* __restrict__ ws)
{
    __shared__ float red[4];
    const float* F = (blockIdx.x >= DD) ? FM : FP;
    const int row = blockIdx.x & (DD - 1);
    float s = 0.f;
    const float4* rowp = (const float4*)&F[(long)row * NN];
    for (int i = threadIdx.x; i < NN / 4; i += blockDim.x) {
        const float4 v = rowp[i];
        s += v.x + v.y + v.z + v.w;
    }
    const int t = threadIdx.x;
    #pragma unroll
    for (int off = 32; off; off >>= 1) s += __shfl_down(s, off);
    if ((t & 63) == 0) red[t >> 6] = s;
    __syncthreads();
    if (t == 0) {
        const double rs = (double)(red[0] + red[1] + red[2] + red[3]);
        atomicAdd(&ws[130], rs * rs);
    }
}

__global__ void finalize_kernel(const double* __restrict__ ws, float* __restrict__ out)
{
    if (threadIdx.x == 0 && blockIdx.x == 0) {
        double s = 0.0;
        #pragma unroll
        for (int k = 0; k < 16; ++k) s += ws[k * 8];
        out[0] = (float)(s + ws[130] + sqrt(ws[128]) + sqrt(ws[129]));
    }
}

extern "C" void kernel_launch(void* const* d_in, const int* in_sizes, int n_in,
                              void* d_out, int out_size, void* d_ws, size_t ws_size,
                              hipStream_t stream)
{
    const float* SU = (const float*)d_in[0];
    const float* SP = (const float*)d_in[1];
    const float* SM = (const float*)d_in[2];
    const float* FP = (const float*)d_in[3];
    const float* FM = (const float*)d_in[4];
    const float* B  = (const float*)d_in[5];
    float*  out = (float*)d_out;
    double* ws  = (double*)d_ws;

    hipMemsetAsync(d_ws, 0, 4096, stream);

    const size_t fb   = (size_t)NN * DD * sizeof(__hip_bfloat16);   // 1 MB
    const size_t need = 4096 + 2 * fb;

    if (ws_size >= need) {
        char* base = (char*)d_ws + 4096;
        __hip_bfloat16* FPt = (__hip_bfloat16*)(base);
        __hip_bfloat16* FMt = (__hip_bfloat16*)(base + fb);
        convert_t_kernel<<<dim3(NN / 128, 2), 256, 0, stream>>>(FP, FM, FPt, FMt);
        gemm_loss_fused<<<512, 256, 0, stream>>>(SU, SP, SM, FPt, FMt, ws);
    } else {
        dim3 grid(NN / 128, NN / 128);
        gemm_loss_mfma<<<grid, 256, 0, stream>>>(SU, FP, FM, 0.0f, ws);
        gemm_loss_mfma<<<grid, 256, 0, stream>>>(SP, FP, FP, 1e-8f, ws);
        gemm_loss_mfma<<<grid, 256, 0, stream>>>(SM, FM, FM, 1e-8f, ws);
    }
    bqc_kernel<<<512, 256, 0, stream>>>(FP, FM, B, ws);
    fdc_kernel<<<256, 256, 0, stream>>>(FP, FM, ws);
    finalize_kernel<<<1, 64, 0, stream>>>(ws, out);
}

// Round 7
// 92.577 us; speedup vs baseline: 1.6122x; 1.3341x over previous
//
#include <hip/hip_runtime.h>
#include <hip/hip_bf16.h>
#include <math.h>

#define NN 4096
#define DD 128

typedef __attribute__((ext_vector_type(8))) short bf16x8;
typedef __attribute__((ext_vector_type(4))) float f32x4;

// ws layout (doubles): gemm-loss slots ws[k*8], k=0..15; ws[128]=bqc1,
// ws[129]=bqc2, ws[130]=fdc.

__device__ __forceinline__ void gload_lds16(const float* g, float* l) {
    __builtin_amdgcn_global_load_lds((const __attribute__((address_space(1))) char*)g,
                                     (__attribute__((address_space(3))) char*)l, 16, 0, 0);
}

// ---- convert F (f32 [d][i], column-reads coalesced) -> bf16 [i][d] ----
__global__ __launch_bounds__(256)
void convert_t_kernel(const float* __restrict__ FP, const float* __restrict__ FM,
                      __hip_bfloat16* __restrict__ FPt, __hip_bfloat16* __restrict__ FMt)
{
    const float* src = blockIdx.y ? FM : FP;
    __hip_bfloat16* dst = blockIdx.y ? FMt : FPt;
    const int t  = threadIdx.x;
    const int il = t & 127;
    const int dh = t >> 7;
    const int i  = blockIdx.x * 128 + il;
    #pragma unroll
    for (int it = 0; it < 8; ++it) {
        const int d0 = dh * 64 + it * 8;
        union { __hip_bfloat162 h[4]; bf16x8 v; } p;
        #pragma unroll
        for (int j = 0; j < 4; ++j) {
            const float a = src[(long)(d0 + 2*j)     * NN + i];
            const float b = src[(long)(d0 + 2*j + 1) * NN + i];
            p.h[j] = __float22bfloat162_rn(make_float2(a, b));
        }
        *(bf16x8*)&dst[(long)i * DD + d0] = p.v;
    }
}

// ---- fused gemm-loss, F fully off the critical path -----------------------
// 512 blocks x 4 waves = 2048 waves. Wave-tile = 32 i x 32 j; 24 tiles/wave.
// Wave w: jt = w & 127 (fixed j0 -> BOTH B-side frag sets hoisted for the
// whole kernel), rr = w >> 7; tile t: z = t/8, it = rr + (t&7)*16.
// Per tile: [issue af(t+1): 8 loads] [issue S(t+1): 4 global_load_lds]
// [vmcnt(12): waits only loads issued LAST iteration] [16 MFMA] [epilogue].
__global__ __launch_bounds__(256, 2)
void gemm_loss_fused(const float* __restrict__ SU, const float* __restrict__ SP,
                     const float* __restrict__ SM,
                     const __hip_bfloat16* __restrict__ FPt_,
                     const __hip_bfloat16* __restrict__ FMt_,
                     double* __restrict__ accum)
{
    __shared__ float sS[4][2][32 * 32];    // per-wave double-buffered S tile
    const int t0   = threadIdx.x;
    const int lane = t0 & 63, wid = t0 >> 6;
    const int l15  = lane & 15, l4 = lane >> 4;
    const int w    = blockIdx.x * 4 + wid;              // 0..2047
    const int jt   = w & 127, rr = w >> 7;
    const int j0   = jt * 32;
    const short* FPt = (const short*)FPt_;
    const short* FMt = (const short*)FMt_;

    // ---- hoisted B-side fragments for both F matrices (loaded ONCE) ----
    bf16x8 bgP[2][4], bgM[2][4];
    #pragma unroll
    for (int n = 0; n < 2; ++n)
        #pragma unroll
        for (int kb = 0; kb < 4; ++kb) {
            const long off = (long)(j0 + n * 16 + l15) * DD + kb * 32 + l4 * 8;
            bgP[n][kb] = *(const bf16x8*)&FPt[off];
            bgM[n][kb] = *(const bf16x8*)&FMt[off];
        }

    float lsum = 0.f;
    bf16x8 afA[2][4], afB[2][4];

#define TILE_Z(tt)   ((tt) >> 3)
#define TILE_I0(tt)  ((rr + (((tt) & 7) << 4)) << 5)

#define ISSUE_AF(tt, dstbuf)                                                   \
    {                                                                          \
        const int z_  = TILE_Z(tt);                                            \
        const int i0_ = TILE_I0(tt);                                           \
        const short* Fa_ = (z_ == 2) ? FMt : FPt;                              \
        _Pragma("unroll")                                                      \
        for (int m = 0; m < 2; ++m)                                            \
            _Pragma("unroll")                                                  \
            for (int kb = 0; kb < 4; ++kb)                                     \
                dstbuf[m][kb] = *(const bf16x8*)&Fa_[(long)(i0_ + m * 16 + l15) * DD + kb * 32 + l4 * 8]; \
    }

#define ISSUE_STAGE(tt)                                                        \
    {                                                                          \
        const int z_  = TILE_Z(tt);                                            \
        const int i0_ = TILE_I0(tt);                                           \
        const float* S_ = (z_ == 0) ? SU : (z_ == 1) ? SP : SM;                \
        const float* src_ = S_ + (long)(i0_ + (lane >> 3)) * NN + j0 + (lane & 7) * 4; \
        float* dst_ = &sS[wid][(tt) & 1][0];                                   \
        _Pragma("unroll")                                                      \
        for (int q_ = 0; q_ < 4; ++q_)                                         \
            gload_lds16(src_ + (long)q_ * 8 * NN, dst_ + q_ * 256);            \
    }

#define TILE_BODY(tt, cur, nxt)                                                \
    {                                                                          \
        const int tc = (tt);                                                   \
        const int tn = (tc < 23) ? tc + 1 : 23;                                \
        ISSUE_AF(tn, nxt);                                                     \
        __builtin_amdgcn_sched_barrier(0);                                     \
        ISSUE_STAGE(tn);                                                       \
        __builtin_amdgcn_sched_barrier(0);                                     \
        asm volatile("s_waitcnt vmcnt(12)");                                   \
        __builtin_amdgcn_sched_barrier(0);                                     \
        const int z_  = TILE_Z(tc);                                            \
        f32x4 acc[2][2] = {};                                                  \
        if (z_ == 1) {                                                         \
            _Pragma("unroll")                                                  \
            for (int kb = 0; kb < 4; ++kb)                                     \
                _Pragma("unroll")                                              \
                for (int m = 0; m < 2; ++m)                                    \
                    _Pragma("unroll")                                          \
                    for (int n = 0; n < 2; ++n)                                \
                        acc[m][n] = __builtin_amdgcn_mfma_f32_16x16x32_bf16(cur[m][kb], bgP[n][kb], acc[m][n], 0, 0, 0); \
        } else {                                                               \
            _Pragma("unroll")                                                  \
            for (int kb = 0; kb < 4; ++kb)                                     \
                _Pragma("unroll")                                              \
                for (int m = 0; m < 2; ++m)                                    \
                    _Pragma("unroll")                                          \
                    for (int n = 0; n < 2; ++n)                                \
                        acc[m][n] = __builtin_amdgcn_mfma_f32_16x16x32_bf16(cur[m][kb], bgM[n][kb], acc[m][n], 0, 0, 0); \
        }                                                                      \
        const float onep = (z_ == 0) ? 1.0f : 1.0f + 1e-8f;                    \
        const float* q = &sS[wid][tc & 1][0];                                  \
        _Pragma("unroll")                                                      \
        for (int m = 0; m < 2; ++m)                                            \
            _Pragma("unroll")                                                  \
            for (int n = 0; n < 2; ++n)                                        \
                _Pragma("unroll")                                              \
                for (int r = 0; r < 4; ++r) {                                  \
                    const float s = q[(m * 16 + l4 * 4 + r) * 32 + n * 16 + l15]; \
                    const float o = 0.5f * acc[m][n][r];                       \
                    lsum += fmaf(-s, o, __logf(o + onep));                     \
                }                                                              \
    }

    // prologue: tile 0's F frags + S tile
    ISSUE_AF(0, afA);
    ISSUE_STAGE(0);

    #pragma unroll 1
    for (int t = 0; t < 24; t += 2) {
        TILE_BODY(t,     afA, afB);
        TILE_BODY(t + 1, afB, afA);
    }
#undef TILE_BODY
#undef ISSUE_STAGE
#undef ISSUE_AF
#undef TILE_Z
#undef TILE_I0

    float v = lsum;
    #pragma unroll
    for (int off = 32; off; off >>= 1) v += __shfl_down(v, off);
    if (lane == 0)
        atomicAdd(accum + ((w & 15) << 3), (double)v);
}

// ---------------- fallback path (round-2 kernel, used if ws too small) ------
__global__ __launch_bounds__(256, 2)
void gemm_loss_mfma(const float* __restrict__ S, const float* __restrict__ F1,
                    const float* __restrict__ F2, float eps, double* __restrict__ accum)
{
    __shared__ char lds[2][128 * 256];
    __shared__ float red[4];
    const int t  = threadIdx.x;
    const int i0 = blockIdx.y * 128;
    const int j0 = blockIdx.x * 128;
    {
        const int il   = t & 127;
        const int half = t >> 7;
        const float* c1 = F1 + i0 + il;
        const float* c2 = F2 + j0 + il;
        char* r1 = lds[0] + il * 256;
        char* r2 = lds[1] + il * 256;
        #pragma unroll
        for (int it = 0; it < 8; ++it) {
            const int q  = half * 8 + it;
            const int d0 = q * 8;
            float a[8], b[8];
            #pragma unroll
            for (int j = 0; j < 8; ++j) {
                a[j] = c1[(long)(d0 + j) * NN];
                b[j] = c2[(long)(d0 + j) * NN];
            }
            union { __hip_bfloat162 h[4]; bf16x8 v; } pa, pb;
            #pragma unroll
            for (int j = 0; j < 4; ++j) {
                pa.h[j] = __float22bfloat162_rn(make_float2(a[2*j], a[2*j+1]));
                pb.h[j] = __float22bfloat162_rn(make_float2(b[2*j], b[2*j+1]));
            }
            const int off = (q ^ (il & 15)) << 4;
            *(bf16x8*)(r1 + off) = pa.v;
            *(bf16x8*)(r2 + off) = pb.v;
        }
    }
    __syncthreads();
    const int lane = t & 63;
    const int wid  = t >> 6;
    const int wr   = wid >> 1, wc = wid & 1;
    const int l15  = lane & 15, l4 = lane >> 4;
    float sreg[4][4][4];
    #pragma unroll
    for (int am = 0; am < 4; ++am)
        #pragma unroll
        for (int r = 0; r < 4; ++r) {
            const long gi    = (long)(i0 + wr * 64 + am * 16 + l4 * 4 + r);
            const long basep = gi * NN + j0 + wc * 64 + l15;
            #pragma unroll
            for (int bn = 0; bn < 4; ++bn)
                sreg[am][bn][r] = S[basep + bn * 16];
        }
    f32x4 acc[4][4] = {};
    #pragma unroll
    for (int kb = 0; kb < 4; ++kb) {
        bf16x8 af[4], bgr[4];
        #pragma unroll
        for (int m = 0; m < 4; ++m) {
            const int ia = wr * 64 + m * 16 + l15;
            af[m] = *(const bf16x8*)(lds[0] + ia * 256 + (((kb * 4 + l4) ^ l15) << 4));
            const int jbq = wc * 64 + m * 16 + l15;
            bgr[m] = *(const bf16x8*)(lds[1] + jbq * 256 + (((kb * 4 + l4) ^ l15) << 4));
        }
        #pragma unroll
        for (int m = 0; m < 4; ++m)
            #pragma unroll
            for (int n = 0; n < 4; ++n)
                acc[m][n] = __builtin_amdgcn_mfma_f32_16x16x32_bf16(af[m], bgr[n], acc[m][n], 0, 0, 0);
    }
    float lsum = 0.f;
    #pragma unroll
    for (int m = 0; m < 4; ++m)
        #pragma unroll
        for (int n = 0; n < 4; ++n)
            #pragma unroll
            for (int r = 0; r < 4; ++r) {
                const float o = 0.5f * acc[m][n][r];
                lsum += fmaf(-sreg[m][n][r], o, __logf(1.0f + o + eps));
            }
    float v = lsum;
    #pragma unroll
    for (int off = 32; off; off >>= 1) v += __shfl_down(v, off);
    if ((t & 63) == 0) red[t >> 6] = v;
    __syncthreads();
    if (t == 0) {
        const float tot = red[0] + red[1] + red[2] + red[3];
        atomicAdd(accum, (double)tot);   // slot 0
    }
}

// ---------------- small kernels ----------------
__global__ __launch_bounds__(256)
void bqc_kernel(const float* __restrict__ FP, const float* __restrict__ FM,
                const float* __restrict__ B, double* __restrict__ ws)
{
    __shared__ float red1[4], red2[4];
    const int n4 = DD * NN / 4;
    float s1 = 0.f, s2 = 0.f;
    for (int i = blockIdx.x * blockDim.x + threadIdx.x; i < n4;
         i += gridDim.x * blockDim.x) {
        const float4 p = ((const float4*)FP)[i];
        const float4 m = ((const float4*)FM)[i];
        const float4 b = ((const float4*)B)[i];
        float d;
        d = p.x - b.x; s1 += d * d;  d = p.y - b.y; s1 += d * d;
        d = p.z - b.z; s1 += d * d;  d = p.w - b.w; s1 += d * d;
        d = m.x - b.x; s2 += d * d;  d = m.y - b.y; s2 += d * d;
        d = m.z - b.z; s2 += d * d;  d = m.w - b.w; s2 += d * d;
    }
    const int t = threadIdx.x;
    #pragma unroll
    for (int off = 32; off; off >>= 1) {
        s1 += __shfl_down(s1, off);
        s2 += __shfl_down(s2, off);
    }
    if ((t & 63) == 0) { red1[t >> 6] = s1; red2[t >> 6] = s2; }
    __syncthreads();
    if (t == 0) {
        atomicAdd(&ws[128], (double)(red1[0] + red1[1] + red1[2] + red1[3]));
        atomicAdd(&ws[129], (double)(red2[0] + red2[1] + red2[2] + red2[3]));
    }
}

__global__ __launch_bounds__(256)
void fdc_kernel(const float* __restrict__ FP, const float* __restrict__ FM,
                double* __restrict__ ws)
{
    __shared__ float red[4];
    const float* F = (blockIdx.x >= DD) ? FM : FP;
    const int row = blockIdx.x & (DD - 1);
    float s = 0.f;
    const float4* rowp = (const float4*)&F[(long)row * NN];
    for (int i = threadIdx.x; i < NN / 4; i += blockDim.x) {
        const float4 v = rowp[i];
        s += v.x + v.y + v.z + v.w;
    }
    const int t = threadIdx.x;
    #pragma unroll
    for (int off = 32; off; off >>= 1) s += __shfl_down(s, off);
    if ((t & 63) == 0) red[t >> 6] = s;
    __syncthreads();
    if (t == 0) {
        const double rs = (double)(red[0] + red[1] + red[2] + red[3]);
        atomicAdd(&ws[130], rs * rs);
    }
}

__global__ void finalize_kernel(const double* __restrict__ ws, float* __restrict__ out)
{
    if (threadIdx.x == 0 && blockIdx.x == 0) {
        double s = 0.0;
        #pragma unroll
        for (int k = 0; k < 16; ++k) s += ws[k * 8];
        out[0] = (float)(s + ws[130] + sqrt(ws[128]) + sqrt(ws[129]));
    }
}

extern "C" void kernel_launch(void* const* d_in, const int* in_sizes, int n_in,
                              void* d_out, int out_size, void* d_ws, size_t ws_size,
                              hipStream_t stream)
{
    const float* SU = (const float*)d_in[0];
    const float* SP = (const float*)d_in[1];
    const float* SM = (const float*)d_in[2];
    const float* FP = (const float*)d_in[3];
    const float* FM = (const float*)d_in[4];
    const float* B  = (const float*)d_in[5];
    float*  out = (float*)d_out;
    double* ws  = (double*)d_ws;

    hipMemsetAsync(d_ws, 0, 4096, stream);

    const size_t fb   = (size_t)NN * DD * sizeof(__hip_bfloat16);   // 1 MB
    const size_t need = 4096 + 2 * fb;

    if (ws_size >= need) {
        char* base = (char*)d_ws + 4096;
        __hip_bfloat16* FPt = (__hip_bfloat16*)(base);
        __hip_bfloat16* FMt = (__hip_bfloat16*)(base + fb);
        convert_t_kernel<<<dim3(NN / 128, 2), 256, 0, stream>>>(FP, FM, FPt, FMt);
        gemm_loss_fused<<<512, 256, 0, stream>>>(SU, SP, SM, FPt, FMt, ws);
    } else {
        dim3 grid(NN / 128, NN / 128);
        gemm_loss_mfma<<<grid, 256, 0, stream>>>(SU, FP, FM, 0.0f, ws);
        gemm_loss_mfma<<<grid, 256, 0, stream>>>(SP, FP, FP, 1e-8f, ws);
        gemm_loss_mfma<<<grid, 256, 0, stream>>>(SM, FM, FM, 1e-8f, ws);
    }
    bqc_kernel<<<512, 256, 0, stream>>>(FP, FM, B, ws);
    fdc_kernel<<<256, 256, 0, stream>>>(FP, FM, ws);
    finalize_kernel<<<1, 64, 0, stream>>>(ws, out);
}